// Round 11
// baseline (401.453 us; speedup 1.0000x reference)
//
#include <hip/hip_runtime.h>
#include <hip/hip_bf16.h>

#define B_    32
#define CIN   128
#define COUT  128
#define NN    128
#define PPAD  130                   // padded p dimension in xT (1 zero col each side)
#define ROWE  (PPAD * CIN)          // 16640 ushorts per padded xT row
#define ACH   512                   // chunks per A slice (128 o x 4 lg)
#define CHROW6 1056                 // 16B chunks per LDS row (66 cols x 16 slots)
#define CH6    (4 * CHROW6)         // 4224 chunks per block x-tile

typedef __attribute__((ext_vector_type(8))) short short8;
typedef __attribute__((ext_vector_type(4))) float float4v;

static __device__ inline unsigned short f2bf(float f) {
    union { float f; unsigned u; } v; v.f = f;
    unsigned u = v.u;
    unsigned r = u + 0x7FFFu + ((u >> 16) & 1u);   // RNE
    return (unsigned short)(r >> 16);
}

// async 16B global->LDS copy (dest = firstlane base + lane*16; issue pattern
// must be whole-wave with lane-consecutive dests; global src MAY be per-lane)
static __device__ inline void gll16(const unsigned short* g, unsigned short* l) {
    __builtin_amdgcn_global_load_lds((const __attribute__((address_space(1))) unsigned int*)g,
                                     (__attribute__((address_space(3))) unsigned int*)l,
                                     16, 0, 0);
}

// ---------------------------------------------------------------------------
// x [B][C][N][N] f32 -> xT [B][row][PPAD][128c] bf16, PRE-SWIZZLED:
// 16B chunk at (pp, slot j) holds channels (j ^ (pp&15))*8 .. +7.
// zero cols pp=0,129. One block per (b,row).
// ---------------------------------------------------------------------------
__global__ __launch_bounds__(256) void xpose_kernel(const float* __restrict__ x,
                                                    unsigned short* __restrict__ xT) {
    int b = blockIdx.x >> 7;
    int i = blockIdx.x & 127;
    __shared__ unsigned short tile[CIN * PPAD];   // [c][p], row stride 130
    int tid = threadIdx.x;
    const float* src = x + ((size_t)(b * CIN) * NN + i) * NN;  // x[b][0][i][0]
    #pragma unroll
    for (int e = 0; e < 64; ++e) {
        int idx = e * 256 + tid;
        int c = idx >> 7;
        int p = idx & 127;
        tile[c * PPAD + p] = f2bf(src[(size_t)c * (NN * NN) + p]);
    }
    __syncthreads();
    unsigned short* dst = xT + (size_t)(b * NN + i) * ROWE;
    #pragma unroll
    for (int e = 0; e < 32; ++e) {
        int pi = e * 256 + tid;          // 0..8191
        int c2 = (pi & 63) * 2;
        int p  = pi >> 6;
        ushort2 v;
        v.x = tile[c2 * PPAD + p];
        v.y = tile[(c2 + 1) * PPAD + p];
        int pp = p + 1;
        int sl = (c2 >> 3) ^ (pp & 15);              // baked XOR swizzle
        *(ushort2*)(dst + (size_t)pp * CIN + sl * 8 + (c2 & 7)) = v;
    }
    if (tid < 128) {                                  // zero pad cols
        dst[tid] = 0;
        dst[(size_t)129 * CIN + tid] = 0;
    }
}

// ---------------------------------------------------------------------------
// kernel [O][C][3][3] f32 -> kT2, transposed slice layout: slice ph = kd*4+cc
// (cc = c>>5); within slice chunk pos = o*4+lg (lg = (c>>3)&3). A wave's
// A-fragment read = one contiguous 1024B window (global, coalesced).
// ---------------------------------------------------------------------------
__global__ __launch_bounds__(256) void ktrans_kernel(const float* __restrict__ kern,
                                                     unsigned short* __restrict__ kT2) {
    int idx = blockIdx.x * 256 + threadIdx.x;     // 0..147455
    if (idx >= COUT * CIN * 9) return;
    int c  = idx & 127;
    int o  = (idx >> 7) & 127;
    int kd = idx >> 14;                           // 0..8
    int k = kd / 3, d = kd % 3;
    float v = kern[(((size_t)o * CIN + c) * 3 + k) * 3 + d];
    size_t chunk = (size_t)(kd * 4 + (c >> 5)) * ACH + o * 4 + ((c >> 3) & 3);
    kT2[chunk * 8 + (c & 7)] = f2bf(v);
}

// ---------------------------------------------------------------------------
// main v11: BARRIER-FREE main loop. Block = 2 rows x 64 px x 128 o (8 waves,
// wave = 64 o x 32 px x 1 row). LDS = read-only x-tile (4 rows x 66 cols) =
// 67,584 B -> 2 blocks/CU, 4 waves/SIMD. A-fragments stream global->VGPR
// (kT2 transposed, L1/L2-hot); B from swizzled LDS. After the single
// prologue __syncthreads, every wave free-runs: no LDS writes, no hazards,
// no barriers -> compiler schedules vmcnt/lgkmcnt finely.
// ---------------------------------------------------------------------------
__global__ __launch_bounds__(512, 4) void conv_mfma11_kernel(
        const unsigned short* __restrict__ xT,
        const unsigned short* __restrict__ kT2,
        const unsigned short* __restrict__ zrow,
        float* __restrict__ out) {
    __shared__ unsigned short xs[CH6 * 8];   // 67,584 B

    // bijective XCD swizzle: 4096 blocks, 8 XCDs, 512-block contiguous slabs
    int wg = blockIdx.x;
    int lb = (wg & 7) * 512 + (wg >> 3);
    int b  = lb >> 7;            // image
    int t  = lb & 127;
    int ph_px = t >> 6;          // px half (0/1)
    int rp = t & 63;             // row pair
    const int pb0 = ph_px * 64;

    int tid  = threadIdx.x;
    int lane = tid & 63;
    int wave = tid >> 6;
    int wo = wave >> 2;            // o half (0/1)
    int wr = (wave >> 1) & 1;      // row of pair
    int wp = wave & 1;             // px 32-half
    int ob  = wo * 64;
    int l15 = lane & 15;
    int lg  = lane >> 4;           // 0..3

    // ---- stage x-tile: rows rp*2-1 .. rp*2+2 (borders -> zrow), cols
    //      pb0..pb0+65, via async gll16; source address is per-lane ----
    {
        const unsigned short* xb  = xT + (size_t)b * NN * ROWE;
        const unsigned short* r0s = (rp == 0)  ? zrow : xb + (size_t)(rp * 2 - 1) * ROWE;
        const unsigned short* r1s = xb + (size_t)(rp * 2) * ROWE;
        const unsigned short* r2s = xb + (size_t)(rp * 2 + 1) * ROWE;
        const unsigned short* r3s = (rp == 63) ? zrow : xb + (size_t)(rp * 2 + 2) * ROWE;
        #pragma unroll
        for (int s = 0; s < 9; ++s) {
            int W = s * 512 + tid;
            if (W < CH6) {                        // group 8 = waves 0,1 whole
                int r   = W / CHROW6;             // 0..3 (per-lane ok: src only)
                int rem = W - r * CHROW6;         // jcol*16 + slot
                const unsigned short* rs = r == 0 ? r0s : (r == 1 ? r1s : (r == 2 ? r2s : r3s));
                gll16(rs + (size_t)(pb0 + (rem >> 4)) * CIN + (rem & 15) * 8,
                      xs + (size_t)W * 8);
            }
        }
    }
    __syncthreads();   // ONLY barrier: x-tile resident & visible

    float4v acc[4][2];
    #pragma unroll
    for (int m = 0; m < 4; ++m) {
        acc[m][0] = (float4v)(0.0f);
        acc[m][1] = (float4v)(0.0f);
    }

    // ---- 36 phases, fully unrolled, no syncs: compiler pipelines ----
    #pragma unroll
    for (int kd = 0; kd < 9; ++kd) {
        const int k = kd / 3, d = kd % 3;
        const unsigned short* srow = xs + (size_t)(wr + k) * CHROW6 * 8;
        #pragma unroll
        for (int cc = 0; cc < 4; ++cc) {
            const int cslot = cc * 4 + lg;
            short8 a[4], bt[2];
            // A from global (contiguous 1024B window per wave, L1/L2-hot)
            const unsigned short* ag = kT2 + ((size_t)(kd * 4 + cc) * ACH) * 8;
            #pragma unroll
            for (int m = 0; m < 4; ++m)
                a[m] = *(const short8*)(ag + ((size_t)(ob + m * 16 + l15) * 4 + lg) * 8);
            // B from swizzled LDS
            int j0 = wp * 32 + l15 + d;           // 0..65 local col
            int j1 = j0 + 16;
            bt[0] = *(const short8*)(srow + ((size_t)j0 * 16 + (cslot ^ (j0 & 15))) * 8);
            bt[1] = *(const short8*)(srow + ((size_t)j1 * 16 + (cslot ^ (j1 & 15))) * 8);
            __builtin_amdgcn_s_setprio(1);
            #pragma unroll
            for (int m = 0; m < 4; ++m) {
                acc[m][0] = __builtin_amdgcn_mfma_f32_16x16x32_bf16(a[m], bt[0], acc[m][0], 0, 0, 0);
                acc[m][1] = __builtin_amdgcn_mfma_f32_16x16x32_bf16(a[m], bt[1], acc[m][1], 0, 0, 0);
            }
            __builtin_amdgcn_s_setprio(0);
        }
    }

    // store: D col = lane&15 -> px, row = (lane>>4)*4 + r -> o
    int row = rp * 2 + wr;
    float* op = out + (size_t)b * COUT * NN * NN + (size_t)row * NN;
    #pragma unroll
    for (int m = 0; m < 4; ++m) {
        #pragma unroll
        for (int n = 0; n < 2; ++n) {
            int p = pb0 + wp * 32 + n * 16 + l15;
            #pragma unroll
            for (int r = 0; r < 4; ++r) {
                int o = ob + m * 16 + lg * 4 + r;
                op[(size_t)o * (NN * NN) + p] = acc[m][n][r];
            }
        }
    }
}

// ---------------------------------------------------------------------------
// fallback: naive direct conv (only if workspace too small)
// ---------------------------------------------------------------------------
__global__ __launch_bounds__(256) void conv_naive_kernel(const float* __restrict__ x,
                                                         const float* __restrict__ kern,
                                                         float* __restrict__ out) {
    size_t idx = (size_t)blockIdx.x * 256 + threadIdx.x;
    int p = idx & 127;
    size_t t = idx >> 7;
    int i = t & 127; t >>= 7;
    int o = t & 127;
    int b = (int)(t >> 7);
    float s = 0.f;
    for (int c = 0; c < CIN; ++c) {
        #pragma unroll
        for (int k = 0; k < 3; ++k) {
            int r = i + k - 1;
            if (r < 0 || r >= NN) continue;
            #pragma unroll
            for (int d = 0; d < 3; ++d) {
                int q = p + d - 1;
                if (q < 0 || q >= NN) continue;
                s += kern[(((size_t)o * CIN + c) * 3 + k) * 3 + d]
                   * x[(((size_t)b * CIN + c) * NN + r) * NN + q];
            }
        }
    }
    out[idx] = s;
}

extern "C" void kernel_launch(void* const* d_in, const int* in_sizes, int n_in,
                              void* d_out, int out_size, void* d_ws, size_t ws_size,
                              hipStream_t stream) {
    const float* x    = (const float*)d_in[0];
    const float* kern = (const float*)d_in[1];
    float* out = (float*)d_out;

    const size_t xT_bytes  = (size_t)B_ * NN * ROWE * 2;        // 136,314,880
    const size_t kT_bytes  = (size_t)9 * 4 * ACH * 8 * 2;       //     294,912
    const size_t zr_bytes  = (size_t)ROWE * 2;                  //      33,280

    if (ws_size >= xT_bytes + kT_bytes + zr_bytes) {
        unsigned short* xT  = (unsigned short*)d_ws;
        unsigned short* kT2 = (unsigned short*)((char*)d_ws + xT_bytes);
        unsigned short* zr  = (unsigned short*)((char*)d_ws + xT_bytes + kT_bytes);
        hipMemsetAsync(zr, 0, zr_bytes, stream);
        hipLaunchKernelGGL(xpose_kernel, dim3(B_ * NN), dim3(256), 0, stream, x, xT);
        hipLaunchKernelGGL(ktrans_kernel, dim3(576), dim3(256), 0, stream, kern, kT2);
        hipLaunchKernelGGL(conv_mfma11_kernel, dim3(4096), dim3(512), 0, stream, xT, kT2, zr, out);
    } else {
        hipLaunchKernelGGL(conv_naive_kernel, dim3(67108864 / 256), dim3(256), 0, stream,
                           x, kern, out);
    }
}

// Round 12
// 304.623 us; speedup vs baseline: 1.3179x; 1.3179x over previous
//
#include <hip/hip_runtime.h>
#include <hip/hip_bf16.h>

#define B_    32
#define CIN   128
#define COUT  128
#define NN    128
#define PPAD  130                   // padded p dimension (1 zero col each side)
#define ROWE  (PPAD * CIN)          // 16640 ushorts per padded xT row

// LDS x-tile: 4 rows x 66 cols x 128 ch, chunked as [r][j][slot16][8ch]
#define JCOLS 66
#define CHROW (JCOLS * 16)          // 1056 chunks per row
#define CHT   (4 * CHROW)           // 4224 chunks per block tile

typedef __attribute__((ext_vector_type(8))) short short8;
typedef __attribute__((ext_vector_type(4))) float float4v;

static __device__ inline unsigned short f2bf(float f) {
    union { float f; unsigned u; } v; v.f = f;
    unsigned u = v.u;
    unsigned r = u + 0x7FFFu + ((u >> 16) & 1u);   // RNE
    return (unsigned short)(r >> 16);
}

// async 16B global->LDS copy (dest = firstlane base + lane*16; keep issue
// wave-uniform; global src may be per-lane)
static __device__ inline void gll16(const unsigned short* g, unsigned short* l) {
    __builtin_amdgcn_global_load_lds((const __attribute__((address_space(1))) unsigned int*)g,
                                     (__attribute__((address_space(3))) unsigned int*)l,
                                     16, 0, 0);
}

// ---------------------------------------------------------------------------
// x [B][C][N][N] f32 -> xT [B][row][PPAD][128c] bf16, PRE-SWIZZLED:
// 16B chunk at (pp, slot j) holds channels (j ^ (pp&15))*8 .. +7.
// zero cols pp=0,129. One block per (b,row).
// ---------------------------------------------------------------------------
__global__ __launch_bounds__(256) void xpose_kernel(const float* __restrict__ x,
                                                    unsigned short* __restrict__ xT) {
    int b = blockIdx.x >> 7;
    int i = blockIdx.x & 127;
    __shared__ unsigned short tile[CIN * PPAD];   // [c][p], row stride 130
    int tid = threadIdx.x;
    const float* src = x + ((size_t)(b * CIN) * NN + i) * NN;  // x[b][0][i][0]
    #pragma unroll
    for (int e = 0; e < 64; ++e) {
        int idx = e * 256 + tid;
        int c = idx >> 7;
        int p = idx & 127;
        tile[c * PPAD + p] = f2bf(src[(size_t)c * (NN * NN) + p]);
    }
    __syncthreads();
    unsigned short* dst = xT + (size_t)(b * NN + i) * ROWE;
    #pragma unroll
    for (int e = 0; e < 32; ++e) {
        int pi = e * 256 + tid;          // 0..8191
        int c2 = (pi & 63) * 2;
        int p  = pi >> 6;
        ushort2 v;
        v.x = tile[c2 * PPAD + p];
        v.y = tile[(c2 + 1) * PPAD + p];
        int pp = p + 1;
        int sl = (c2 >> 3) ^ (pp & 15);              // baked XOR swizzle
        *(ushort2*)(dst + (size_t)pp * CIN + sl * 8 + (c2 & 7)) = v;
    }
    if (tid < 128) {                                  // zero pad cols
        dst[tid] = 0;
        dst[(size_t)129 * CIN + tid] = 0;
    }
}

// ---------------------------------------------------------------------------
// kernel [O][C][3][3] f32 -> kT2 [kd][cslot16][o][8c] bf16  (kd = k*3+d)
// (v6 layout: wave A-read = 4 x 256B-contiguous windows, proven)
// ---------------------------------------------------------------------------
__global__ __launch_bounds__(256) void ktrans_kernel(const float* __restrict__ kern,
                                                     unsigned short* __restrict__ kT2) {
    int idx = blockIdx.x * 256 + threadIdx.x;     // 0..147455
    if (idx >= COUT * CIN * 9) return;
    int c  = idx & 127;
    int o  = (idx >> 7) & 127;
    int kd = idx >> 14;                           // 0..8
    int k = kd / 3, d = kd % 3;
    float v = kern[(((size_t)o * CIN + c) * 3 + k) * 3 + d];
    kT2[((size_t)(kd * 16 + (c >> 3)) * 128 + o) * 8 + (c & 7)] = f2bf(v);
}

// ---------------------------------------------------------------------------
// main v12: v6 structure (barrier-free main loop, block = 2 rows x 64 px x
// 128 o, 8 waves, 67.6 KB LDS -> 2 blocks/CU, A global->VGPR, B swizzled LDS)
// + EXPLICIT register double-buffer: phase ph+1's A/B fragments load while
// phase ph's 8 MFMAs run. All buffer indices compile-time (full unroll).
// No setprio (v11 regression). One barrier total (+1 for border blocks).
// ---------------------------------------------------------------------------
__global__ __launch_bounds__(512, 4) void conv_mfma12_kernel(
        const unsigned short* __restrict__ xT,
        const unsigned short* __restrict__ kT2,
        float* __restrict__ out) {
    __shared__ unsigned short xs[CHT * 8];   // 67,584 B

    // bijective XCD swizzle: 4096 blocks, 8 XCDs, 512-block contiguous slabs
    int wg = blockIdx.x;
    int lb = (wg & 7) * 512 + (wg >> 3);
    int b  = lb >> 7;            // image
    int t  = lb & 127;
    int ph_px = t >> 6;          // px half (0/1)
    int rp = t & 63;             // row pair
    const int pb0 = ph_px * 64;

    int tid  = threadIdx.x;
    int lane = tid & 63;
    int wave = tid >> 6;
    int wo = wave >> 2;            // o half (0/1)
    int wr = (wave >> 1) & 1;      // row of pair
    int wp = wave & 1;             // px 32-half
    int ob  = wo * 64;
    int l15 = lane & 15;
    int lg  = lane >> 4;           // 0..3

    // ---- stage 4 x-rows (rp*2-1 .. rp*2+2), cols pb0..pb0+65, clamped ----
    {
        const unsigned short* xrow_base = xT + (size_t)b * NN * ROWE;
        #pragma unroll
        for (int s = 0; s < 9; ++s) {
            int W = s * 512 + tid;
            if (W < CHT) {                       // full waves (4224 = 66*64)
                int r    = W / CHROW;            // 0..3
                int rem  = W - r * CHROW;        // j*16 + slot
                int grow = rp * 2 - 1 + r;       // -1..128
                int growc = grow < 0 ? 0 : (grow > NN - 1 ? NN - 1 : grow);
                gll16(xrow_base + (size_t)growc * ROWE
                          + ((size_t)pb0 + (rem >> 4)) * CIN + (rem & 15) * 8,
                      xs + (size_t)W * 8);
            }
        }
    }
    __syncthreads();   // drains vmcnt -> staged data visible

    // ---- zero halo rows outside the image (block-uniform branches) ----
    if (rp == 0) {
        for (int W = tid; W < CHROW; W += 512)                    // row r=0
            *(short8*)(xs + (size_t)W * 8) = (short8)(0);
    }
    if (rp == 63) {
        for (int W = 3 * CHROW + tid; W < 4 * CHROW; W += 512)    // row r=3
            *(short8*)(xs + (size_t)W * 8) = (short8)(0);
    }
    if (rp == 0 || rp == 63) __syncthreads();

    float4v acc[4][2];
    #pragma unroll
    for (int m = 0; m < 4; ++m) {
        acc[m][0] = (float4v)(0.0f);
        acc[m][1] = (float4v)(0.0f);
    }

    short8 aR[2][4], bR[2][2];

    // ---- preload phase-0 fragments (kd=0 -> k=0,d=0; cc=0) ----
    {
        const unsigned short* krow = kT2;        // kd=0
        #pragma unroll
        for (int m = 0; m < 4; ++m)
            aR[0][m] = *(const short8*)(krow + ((size_t)(lg * 128) + ob + m * 16 + l15) * 8);
        const unsigned short* srow = xs + (size_t)wr * CHROW * 8;
        int j0 = wp * 32 + l15;
        int j1 = j0 + 16;
        bR[0][0] = *(const short8*)(srow + ((size_t)j0 * 16 + (lg ^ (j0 & 15))) * 8);
        bR[0][1] = *(const short8*)(srow + ((size_t)j1 * 16 + (lg ^ (j1 & 15))) * 8);
    }

    // ---- 36 phases, barrier-free; prefetch ph+1 under ph's MFMAs ----
    #pragma unroll
    for (int ph = 0; ph < 36; ++ph) {
        const int q = ph & 1;
        if (ph < 35) {
            const int p1  = ph + 1;
            const int kd1 = p1 >> 2, cc1 = p1 & 3;
            const int k1  = kd1 / 3, d1 = kd1 % 3;
            const int cslot1 = cc1 * 4 + lg;
            const unsigned short* krow = kT2 + (size_t)kd1 * 16 * 128 * 8;
            #pragma unroll
            for (int m = 0; m < 4; ++m)
                aR[q ^ 1][m] = *(const short8*)(krow +
                    ((size_t)(cslot1 * 128) + ob + m * 16 + l15) * 8);
            const unsigned short* srow = xs + (size_t)(wr + k1) * CHROW * 8;
            int j0 = wp * 32 + l15 + d1;         // 0..65 local col
            int j1 = j0 + 16;
            bR[q ^ 1][0] = *(const short8*)(srow + ((size_t)j0 * 16 + (cslot1 ^ (j0 & 15))) * 8);
            bR[q ^ 1][1] = *(const short8*)(srow + ((size_t)j1 * 16 + (cslot1 ^ (j1 & 15))) * 8);
        }
        #pragma unroll
        for (int m = 0; m < 4; ++m) {
            acc[m][0] = __builtin_amdgcn_mfma_f32_16x16x32_bf16(aR[q][m], bR[q][0], acc[m][0], 0, 0, 0);
            acc[m][1] = __builtin_amdgcn_mfma_f32_16x16x32_bf16(aR[q][m], bR[q][1], acc[m][1], 0, 0, 0);
        }
    }

    // store: D col = lane&15 -> px, row = (lane>>4)*4 + r -> o
    int row = rp * 2 + wr;
    float* op = out + (size_t)b * COUT * NN * NN + (size_t)row * NN;
    #pragma unroll
    for (int m = 0; m < 4; ++m) {
        #pragma unroll
        for (int n = 0; n < 2; ++n) {
            int p = pb0 + wp * 32 + n * 16 + l15;
            #pragma unroll
            for (int r = 0; r < 4; ++r) {
                int o = ob + m * 16 + lg * 4 + r;
                op[(size_t)o * (NN * NN) + p] = acc[m][n][r];
            }
        }
    }
}

// ---------------------------------------------------------------------------
// fallback: naive direct conv (only if workspace too small)
// ---------------------------------------------------------------------------
__global__ __launch_bounds__(256) void conv_naive_kernel(const float* __restrict__ x,
                                                         const float* __restrict__ kern,
                                                         float* __restrict__ out) {
    size_t idx = (size_t)blockIdx.x * 256 + threadIdx.x;
    int p = idx & 127;
    size_t t = idx >> 7;
    int i = t & 127; t >>= 7;
    int o = t & 127;
    int b = (int)(t >> 7);
    float s = 0.f;
    for (int c = 0; c < CIN; ++c) {
        #pragma unroll
        for (int k = 0; k < 3; ++k) {
            int r = i + k - 1;
            if (r < 0 || r >= NN) continue;
            #pragma unroll
            for (int d = 0; d < 3; ++d) {
                int q = p + d - 1;
                if (q < 0 || q >= NN) continue;
                s += kern[(((size_t)o * CIN + c) * 3 + k) * 3 + d]
                   * x[(((size_t)b * CIN + c) * NN + r) * NN + q];
            }
        }
    }
    out[idx] = s;
}

extern "C" void kernel_launch(void* const* d_in, const int* in_sizes, int n_in,
                              void* d_out, int out_size, void* d_ws, size_t ws_size,
                              hipStream_t stream) {
    const float* x    = (const float*)d_in[0];
    const float* kern = (const float*)d_in[1];
    float* out = (float*)d_out;

    const size_t xT_bytes  = (size_t)B_ * NN * ROWE * 2;        // 136,314,880
    const size_t kT_bytes  = (size_t)9 * 16 * 128 * 8 * 2;      //     294,912

    if (ws_size >= xT_bytes + kT_bytes) {
        unsigned short* xT  = (unsigned short*)d_ws;
        unsigned short* kT2 = (unsigned short*)((char*)d_ws + xT_bytes);
        hipLaunchKernelGGL(xpose_kernel, dim3(B_ * NN), dim3(256), 0, stream, x, xT);
        hipLaunchKernelGGL(ktrans_kernel, dim3(576), dim3(256), 0, stream, kern, kT2);
        hipLaunchKernelGGL(conv_mfma12_kernel, dim3(4096), dim3(512), 0, stream, xT, kT2, out);
    } else {
        hipLaunchKernelGGL(conv_naive_kernel, dim3(67108864 / 256), dim3(256), 0, stream,
                           x, kern, out);
    }
}

// Round 13
// 271.466 us; speedup vs baseline: 1.4788x; 1.1221x over previous
//
#include <hip/hip_runtime.h>
#include <hip/hip_bf16.h>

#define B_    32
#define CIN   128
#define COUT  128
#define NN    128
#define PPAD  130                   // padded p dimension (1 zero col each side)
#define CHROW 2080                  // 16B chunks per padded LDS row (130*16)
#define XCHT  (4 * CHROW)           // 8320 chunks: 4-row x-tile
#define ACH   512                   // chunks per A slice (4 cslots x 128 o)

typedef __attribute__((ext_vector_type(8))) short short8;
typedef __attribute__((ext_vector_type(4))) float float4v;
typedef __attribute__((ext_vector_type(4))) float f32x4;

static __device__ inline unsigned short f2bf(float f) {
    union { float f; unsigned u; } v; v.f = f;
    unsigned u = v.u;
    unsigned r = u + 0x7FFFu + ((u >> 16) & 1u);   // RNE
    return (unsigned short)(r >> 16);
}

// async 16B global->LDS copy (dest = firstlane base + lane*16; wave-uniform)
static __device__ inline void gll16(const unsigned short* g, unsigned short* l) {
    __builtin_amdgcn_global_load_lds((const __attribute__((address_space(1))) unsigned int*)g,
                                     (__attribute__((address_space(3))) unsigned int*)l,
                                     16, 0, 0);
}

// ---------------------------------------------------------------------------
// kernel [O][C][3][3] f32 -> kT2 [kd][cslot16][o][8c] bf16 (kd = k*3+d)
// slice ph = kd*4+cc covers cslots cc*4..cc*4+3; chunk-in-slice = lg*128 + o.
// ---------------------------------------------------------------------------
__global__ __launch_bounds__(256) void ktrans_kernel(const float* __restrict__ kern,
                                                     unsigned short* __restrict__ kT2) {
    int idx = blockIdx.x * 256 + threadIdx.x;     // 0..147455
    if (idx >= COUT * CIN * 9) return;
    int c  = idx & 127;
    int o  = (idx >> 7) & 127;
    int kd = idx >> 14;                           // 0..8
    int k = kd / 3, d = kd % 3;
    float v = kern[(((size_t)o * CIN + c) * 3 + k) * 3 + d];
    kT2[((size_t)(kd * 16 + (c >> 3)) * 128 + o) * 8 + (c & 7)] = f2bf(v);
}

// ---------------------------------------------------------------------------
// v13 FUSED: transpose+conv in one kernel. Block = 2 rows x 128 px x 128 o,
// 512 thr. LDS = padded swizzled x-tile [4][130][16][8] (133,120 B) + A-slice
// 3-buffer (24,576 B) = 157,696 B -> 1 block/CU.
// Raw x f32 read coalesced -> cvt bf16 -> ds_write_b64 transposed+swizzled.
// Rows 0,1 in prologue; rows 2,3 loads spread over phases 0-3, written at
// phases 4/6 (first use ph 12/24). A pipeline = v8's (3-buf gll16, counted
// vmcnt). Borders: block-uniform skip-write + zero.
// ---------------------------------------------------------------------------
__global__ __launch_bounds__(512, 1) void conv_fused_kernel(
        const float* __restrict__ x,
        const unsigned short* __restrict__ kT2,
        float* __restrict__ out) {
    __shared__ unsigned short xs[(XCHT + 3 * ACH) * 8];   // 157,696 B

    // bijective XCD swizzle: 2048 blocks, 8 XCDs, 256-block contiguous slabs
    int wg = blockIdx.x;
    int lb = (wg & 7) * 256 + (wg >> 3);
    int b  = lb >> 6;            // image
    int rp = lb & 63;            // row pair

    int tid  = threadIdx.x;
    int lane = tid & 63;
    int wave = tid >> 6;
    int wo = wave >> 2;            // o half (0/1)
    int wr = (wave >> 1) & 1;      // row of pair
    int wq = wave & 1;             // px 64-half
    int ob  = wo * 64;
    int pb  = wq * 64;
    int l15 = lane & 15;
    int lg  = lane >> 4;           // 0..3

    // transpose mapping: thread covers channels c0..c0+3, pixels q*8..q*8+7
    const int c0 = (tid >> 4) * 4;   // 0..124 step 4
    const int q  = tid & 15;
    const float* xb = x + (size_t)b * CIN * NN * NN;
    const int g0c = (rp == 0)  ? 0   : rp * 2 - 1;   // clamped source rows
    const int g1  = rp * 2;
    const int g2  = rp * 2 + 1;
    const int g3c = (rp == 63) ? 127 : rp * 2 + 2;

    // write one transposed b64 (4 channels c0..c0+3 at pixel p) into LDS row r
    // chunk(r,pp,j): content c-slot = j ^ (pp&15); our j = (c0>>3)^(pp&15).
    #define TWRITE(r, p, v0, v1, v2, v3)                                        \
        {                                                                       \
            int pp_ = (p) + 1;                                                  \
            size_t ch_ = (size_t)(r) * CHROW + (size_t)pp_ * 16                 \
                       + ((c0 >> 3) ^ (pp_ & 15));                              \
            union { unsigned short u[4]; uint2 w; } pk_;                        \
            pk_.u[0] = f2bf(v0); pk_.u[1] = f2bf(v1);                           \
            pk_.u[2] = f2bf(v2); pk_.u[3] = f2bf(v3);                           \
            *(uint2*)(xs + ch_ * 8 + (c0 & 7)) = pk_.w;                         \
        }

    // ---- prologue ----
    f32x4 L0[8], L1[8];
    #pragma unroll
    for (int j = 0; j < 4; ++j)
        #pragma unroll
        for (int h = 0; h < 2; ++h)
            L0[j * 2 + h] = *(const f32x4*)(xb + ((size_t)(c0 + j) * NN + g0c) * NN + q * 8 + h * 4);
    #pragma unroll
    for (int j = 0; j < 4; ++j)
        #pragma unroll
        for (int h = 0; h < 2; ++h)
            L1[j * 2 + h] = *(const f32x4*)(xb + ((size_t)(c0 + j) * NN + g1) * NN + q * 8 + h * 4);
    gll16(kT2 + (size_t)tid * 8,         xs + (size_t)(XCHT + tid) * 8);         // A0
    gll16(kT2 + (size_t)(ACH + tid) * 8, xs + (size_t)(XCHT + ACH + tid) * 8);   // A1
    asm volatile("s_waitcnt vmcnt(1)" ::: "memory");   // rows01 + A0 landed; A1 flying

    if (rp != 0) {
        #pragma unroll
        for (int h = 0; h < 2; ++h)
            #pragma unroll
            for (int i = 0; i < 4; ++i)
                TWRITE(0, q * 8 + h * 4 + i, L0[0 * 2 + h][i], L0[1 * 2 + h][i],
                                             L0[2 * 2 + h][i], L0[3 * 2 + h][i]);
    } else {
        for (int W = tid; W < CHROW; W += 512)         // zero row r=0
            *(short8*)(xs + (size_t)W * 8) = (short8)(0);
    }
    #pragma unroll
    for (int h = 0; h < 2; ++h)
        #pragma unroll
        for (int i = 0; i < 4; ++i)
            TWRITE(1, q * 8 + h * 4 + i, L1[0 * 2 + h][i], L1[1 * 2 + h][i],
                                         L1[2 * 2 + h][i], L1[3 * 2 + h][i]);
    // zero pad cols pp=0,129 for all 4 rows (128 chunks)
    if (tid < 128) {
        int r_  = tid >> 5;
        int pp_ = ((tid >> 4) & 1) ? 129 : 0;
        int j_  = tid & 15;
        *(short8*)(xs + ((size_t)r_ * CHROW + (size_t)pp_ * 16 + j_) * 8) = (short8)(0);
    }
    asm volatile("s_waitcnt lgkmcnt(0)" ::: "memory");
    __builtin_amdgcn_s_barrier();

    float4v acc[4][4];
    #pragma unroll
    for (int m = 0; m < 4; ++m)
        #pragma unroll
        for (int n = 0; n < 4; ++n)
            acc[m][n] = (float4v)(0.0f);

    f32x4 L2[8], L3[8];

    // ---- 36 phases; ph = (kd = ph>>2, cc = ph&3); A buf = slice % 3 ----
    // vmcnt queue (derived): prologue->[A1]; ph0..6 waits 5,9,8,8,5,1,1;
    // steady 1; ph34 -> 0.
    #pragma unroll
    for (int ph = 0; ph < 36; ++ph) {
        const int kd = ph >> 2, cc = ph & 3;
        const int k = kd / 3, d = kd % 3;
        // A-slice issue (slice ph+2 into buf (ph+2)%3; that buf was read ph-1)
        if (ph + 2 <= 35)
            gll16(kT2 + ((size_t)(ph + 2) * ACH + tid) * 8,
                  xs + (size_t)(XCHT + ((ph + 2) % 3) * ACH + tid) * 8);
        // rows 2,3 f32 load issues: 4 float4 per phase, phases 0-3
        if (ph == 0 || ph == 1) {
            #pragma unroll
            for (int j = 0; j < 4; ++j)
                L2[j * 2 + ph] = *(const f32x4*)(xb + ((size_t)(c0 + j) * NN + g2) * NN + q * 8 + ph * 4);
        }
        if (ph == 2 || ph == 3) {
            const int h = ph - 2;
            #pragma unroll
            for (int j = 0; j < 4; ++j)
                L3[j * 2 + h] = *(const f32x4*)(xb + ((size_t)(c0 + j) * NN + g3c) * NN + q * 8 + h * 4);
        }
        // deferred transpose-writes (data forced-done by earlier vmcnt waits)
        if (ph == 4) {     // row2 (r=2), first used at phase 12
            #pragma unroll
            for (int h = 0; h < 2; ++h)
                #pragma unroll
                for (int i = 0; i < 4; ++i)
                    TWRITE(2, q * 8 + h * 4 + i, L2[0 * 2 + h][i], L2[1 * 2 + h][i],
                                                 L2[2 * 2 + h][i], L2[3 * 2 + h][i]);
        }
        if (ph == 6) {     // row3 (r=3), first used at phase 24
            if (rp != 63) {
                #pragma unroll
                for (int h = 0; h < 2; ++h)
                    #pragma unroll
                    for (int i = 0; i < 4; ++i)
                        TWRITE(3, q * 8 + h * 4 + i, L3[0 * 2 + h][i], L3[1 * 2 + h][i],
                                                     L3[2 * 2 + h][i], L3[3 * 2 + h][i]);
            } else {
                for (int W = 3 * CHROW + tid; W < 4 * CHROW; W += 512)
                    *(short8*)(xs + (size_t)W * 8) = (short8)(0);
            }
        }
        // in-phase fragment reads (v8 style)
        short8 a[4], bt[4];
        {
            const unsigned short* ab = xs + (size_t)(XCHT + (ph % 3) * ACH) * 8;
            #pragma unroll
            for (int m = 0; m < 4; ++m)
                a[m] = *(const short8*)(ab + ((size_t)lg * 128 + ob + m * 16 + l15) * 8);
            const unsigned short* srow = xs + (size_t)(wr + k) * CHROW * 8;
            #pragma unroll
            for (int n = 0; n < 4; ++n) {
                int pp = pb + n * 16 + l15 + d;          // 0..129 (pads zero)
                bt[n] = *(const short8*)(srow + ((size_t)pp * 16 + ((cc * 4 + lg) ^ (pp & 15))) * 8);
            }
        }
        __builtin_amdgcn_s_setprio(1);
        #pragma unroll
        for (int m = 0; m < 4; ++m)
            #pragma unroll
            for (int n = 0; n < 4; ++n)
                acc[m][n] = __builtin_amdgcn_mfma_f32_16x16x32_bf16(a[m], bt[n], acc[m][n], 0, 0, 0);
        __builtin_amdgcn_s_setprio(0);
        // per-phase counted waits (compile-time constants under full unroll)
        if (ph == 4 || ph == 6)
            asm volatile("s_waitcnt lgkmcnt(0)" ::: "memory");   // drain ds_writes
        if      (ph == 0) asm volatile("s_waitcnt vmcnt(5)" ::: "memory");
        else if (ph == 1) asm volatile("s_waitcnt vmcnt(9)" ::: "memory");
        else if (ph == 2) asm volatile("s_waitcnt vmcnt(8)" ::: "memory");
        else if (ph == 3) asm volatile("s_waitcnt vmcnt(8)" ::: "memory");
        else if (ph == 4) asm volatile("s_waitcnt vmcnt(5)" ::: "memory");
        else if (ph == 5) asm volatile("s_waitcnt vmcnt(1)" ::: "memory");
        else if (ph == 34) asm volatile("s_waitcnt vmcnt(0)" ::: "memory");
        else if (ph <= 33) asm volatile("s_waitcnt vmcnt(1)" ::: "memory");
        if (ph < 35) __builtin_amdgcn_s_barrier();
    }
    #undef TWRITE

    // store: D col = lane&15 -> px, row = (lane>>4)*4 + r -> o
    int row = rp * 2 + wr;
    float* op = out + (size_t)b * COUT * NN * NN + (size_t)row * NN;
    #pragma unroll
    for (int m = 0; m < 4; ++m) {
        #pragma unroll
        for (int n = 0; n < 4; ++n) {
            int p = pb + n * 16 + l15;
            #pragma unroll
            for (int r = 0; r < 4; ++r) {
                int o = ob + m * 16 + lg * 4 + r;
                op[(size_t)o * (NN * NN) + p] = acc[m][n][r];
            }
        }
    }
}

// ---------------------------------------------------------------------------
// fallback: naive direct conv (only if workspace too small)
// ---------------------------------------------------------------------------
__global__ __launch_bounds__(256) void conv_naive_kernel(const float* __restrict__ x,
                                                         const float* __restrict__ kern,
                                                         float* __restrict__ out) {
    size_t idx = (size_t)blockIdx.x * 256 + threadIdx.x;
    int p = idx & 127;
    size_t t = idx >> 7;
    int i = t & 127; t >>= 7;
    int o = t & 127;
    int b = (int)(t >> 7);
    float s = 0.f;
    for (int c = 0; c < CIN; ++c) {
        #pragma unroll
        for (int k = 0; k < 3; ++k) {
            int r = i + k - 1;
            if (r < 0 || r >= NN) continue;
            #pragma unroll
            for (int d = 0; d < 3; ++d) {
                int q2 = p + d - 1;
                if (q2 < 0 || q2 >= NN) continue;
                s += kern[(((size_t)o * CIN + c) * 3 + k) * 3 + d]
                   * x[(((size_t)b * CIN + c) * NN + r) * NN + q2];
            }
        }
    }
    out[idx] = s;
}

extern "C" void kernel_launch(void* const* d_in, const int* in_sizes, int n_in,
                              void* d_out, int out_size, void* d_ws, size_t ws_size,
                              hipStream_t stream) {
    const float* x    = (const float*)d_in[0];
    const float* kern = (const float*)d_in[1];
    float* out = (float*)d_out;

    const size_t kT_bytes = (size_t)9 * 16 * 128 * 8 * 2;       // 294,912

    if (ws_size >= kT_bytes) {
        unsigned short* kT2 = (unsigned short*)d_ws;
        hipLaunchKernelGGL(ktrans_kernel, dim3(576), dim3(256), 0, stream, kern, kT2);
        hipLaunchKernelGGL(conv_fused_kernel, dim3(2048), dim3(512), 0, stream, x, kT2, out);
    } else {
        hipLaunchKernelGGL(conv_naive_kernel, dim3(67108864 / 256), dim3(256), 0, stream,
                           x, kern, out);
    }
}

// Round 14
// 261.998 us; speedup vs baseline: 1.5323x; 1.0361x over previous
//
#include <hip/hip_runtime.h>
#include <hip/hip_bf16.h>

#define B_    32
#define CIN   128
#define COUT  128
#define NN    128
#define PPAD  130                   // padded p dimension in xT (1 zero col each side)
#define ROWE  (PPAD * CIN)          // 16640 ushorts per padded xT row
#define XCH   8192                  // x chunks in LDS: 4 rows * 128 px * 16 slots
#define ACH   512                   // chunks per A slice: 128 o x 4 lg

typedef __attribute__((ext_vector_type(8))) short short8;
typedef __attribute__((ext_vector_type(4))) float float4v;

static __device__ inline unsigned short f2bf(float f) {
    union { float f; unsigned u; } v; v.f = f;
    unsigned u = v.u;
    unsigned r = u + 0x7FFFu + ((u >> 16) & 1u);   // RNE
    return (unsigned short)(r >> 16);
}

// async 16B global->LDS copy (dest = firstlane base + lane*16; keep issue
// wave-uniform, no divergence)
static __device__ inline void gll16(const unsigned short* g, unsigned short* l) {
    __builtin_amdgcn_global_load_lds((const __attribute__((address_space(1))) unsigned int*)g,
                                     (__attribute__((address_space(3))) unsigned int*)l,
                                     16, 0, 0);
}

// ---------------------------------------------------------------------------
// x [B][C][N][N] f32 -> xT [B][row][PPAD][128c] bf16, PRE-SWIZZLED:
// 16B chunk at (pp, slot j) holds channels (j ^ (pp&15))*8 .. +7.
// zero cols pp=0,129. One block per (b,row).
// ---------------------------------------------------------------------------
__global__ __launch_bounds__(256) void xpose_kernel(const float* __restrict__ x,
                                                    unsigned short* __restrict__ xT) {
    int b = blockIdx.x >> 7;
    int i = blockIdx.x & 127;
    __shared__ unsigned short tile[CIN * PPAD];   // [c][p], row stride 130
    int tid = threadIdx.x;
    const float* src = x + ((size_t)(b * CIN) * NN + i) * NN;  // x[b][0][i][0]
    #pragma unroll
    for (int e = 0; e < 64; ++e) {
        int idx = e * 256 + tid;
        int c = idx >> 7;
        int p = idx & 127;
        tile[c * PPAD + p] = f2bf(src[(size_t)c * (NN * NN) + p]);
    }
    __syncthreads();
    unsigned short* dst = xT + (size_t)(b * NN + i) * ROWE;
    #pragma unroll
    for (int e = 0; e < 32; ++e) {
        int pi = e * 256 + tid;          // 0..8191
        int c2 = (pi & 63) * 2;
        int p  = pi >> 6;
        ushort2 v;
        v.x = tile[c2 * PPAD + p];
        v.y = tile[(c2 + 1) * PPAD + p];
        int pp = p + 1;
        int sl = (c2 >> 3) ^ (pp & 15);              // baked XOR swizzle
        *(ushort2*)(dst + (size_t)pp * CIN + sl * 8 + (c2 & 7)) = v;
    }
    if (tid < 128) {                                  // zero pad cols
        dst[tid] = 0;
        dst[(size_t)129 * CIN + tid] = 0;
    }
}

// ---------------------------------------------------------------------------
// kernel [O][C][3][3] f32 -> kT2, TRANSPOSED slice layout: slice ph = kd*4+cc
// (cc = c>>5); within slice chunk pos = o*4+lg (lg = (c>>3)&3). A wave's
// A-fragment read = one contiguous 1024B LDS window (conflict-free).
// ---------------------------------------------------------------------------
__global__ __launch_bounds__(256) void ktrans_kernel(const float* __restrict__ kern,
                                                     unsigned short* __restrict__ kT2) {
    int idx = blockIdx.x * 256 + threadIdx.x;     // 0..147455
    if (idx >= COUT * CIN * 9) return;
    int c  = idx & 127;
    int o  = (idx >> 7) & 127;
    int kd = idx >> 14;                           // 0..8
    int k = kd / 3, d = kd % 3;
    float v = kern[(((size_t)o * CIN + c) * 3 + k) * 3 + d];
    size_t chunk = (size_t)(kd * 4 + (c >> 5)) * ACH + o * 4 + ((c >> 3) & 3);
    kT2[chunk * 8 + (c & 7)] = f2bf(v);
}

// ---------------------------------------------------------------------------
// main v14 = v9 + transposed A layout (the only untested combination:
// clean contiguous A-reads AND no per-phase lgkmcnt(0)).
// Register double-buffered fragments (prefetch ph+1 under ph's MFMAs),
// 4-deep A-slice gll16 pipeline (issue ph+3 at ph; vmcnt(1) drains ph+2).
// LDS = x-tile 128 KB + 4x8 KB A slices = 163,840 B.
// ---------------------------------------------------------------------------
__global__ __launch_bounds__(512, 1) void conv_mfma14_kernel(const unsigned short* __restrict__ xT,
                                                             const unsigned short* __restrict__ kT2,
                                                             float* __restrict__ out) {
    __shared__ unsigned short xs[(XCH + 4 * ACH) * 8];   // 163,840 B

    // bijective XCD swizzle: 2048 blocks, 8 XCDs, 256-block contiguous slabs
    int wg = blockIdx.x;
    int lb = (wg & 7) * 256 + (wg >> 3);
    int b  = lb >> 6;            // image
    int rp = lb & 63;            // row pair

    int tid  = threadIdx.x;
    int lane = tid & 63;
    int wave = tid >> 6;
    int wo = wave >> 2;            // o half (0/1)
    int wr = (wave >> 1) & 1;      // row of pair
    int wq = wave & 1;             // px 64-half
    int ob  = wo * 64;
    int pb  = wq * 64;
    int l15 = lane & 15;
    int lg  = lane >> 4;           // 0..3

    // ---- prologue: stage x tile + A slices 0,1,2 ----
    {
        const unsigned short* xrow_base = xT + (size_t)b * NN * ROWE;
        #pragma unroll
        for (int s = 0; s < 16; ++s) {
            int W   = s * 512 + tid;            // 0..8191
            int r   = W >> 11;                  // 0..3
            int rem = W & 2047;                 // p*16 + j
            int grow = rp * 2 - 1 + r;          // -1..128
            int growc = grow < 0 ? 0 : (grow > NN - 1 ? NN - 1 : grow);
            // src chunk = (p+1)*16 + j = rem + 16  (skip pad col 0)
            gll16(xrow_base + (size_t)growc * ROWE + (size_t)(rem + 16) * 8,
                  xs + (size_t)W * 8);
        }
        gll16(kT2 + (size_t)tid * 8,             xs + (size_t)(XCH + tid) * 8);
        gll16(kT2 + (size_t)(ACH + tid) * 8,     xs + (size_t)(XCH + ACH + tid) * 8);
        gll16(kT2 + (size_t)(2 * ACH + tid) * 8, xs + (size_t)(XCH + 2 * ACH + tid) * 8);
    }
    asm volatile("s_waitcnt vmcnt(1)" ::: "memory");   // x + slices 0,1 landed; 2 flying
    __builtin_amdgcn_s_barrier();

    // ---- zero halo rows outside the image (block-uniform) ----
    if (rp == 0) {
        for (int W = tid; W < 2048; W += 512)
            *(short8*)(xs + (size_t)W * 8) = (short8)(0);
    }
    if (rp == 63) {
        for (int W = 3 * 2048 + tid; W < 4 * 2048; W += 512)
            *(short8*)(xs + (size_t)W * 8) = (short8)(0);
    }
    if (rp == 0 || rp == 63) {
        asm volatile("s_waitcnt lgkmcnt(0)" ::: "memory");
        __builtin_amdgcn_s_barrier();
    }

    float4v acc[4][4];
    #pragma unroll
    for (int m = 0; m < 4; ++m)
        #pragma unroll
        for (int n = 0; n < 4; ++n)
            acc[m][n] = (float4v)(0.0f);

    short8 aR[2][4], bR[2][4];

    // ---- load phase-0 fragments (kd=0 -> k=0,d=0; cc=0; A buf 0) ----
    {
        const unsigned short* ab = xs + (size_t)XCH * 8;
        #pragma unroll
        for (int m = 0; m < 4; ++m)
            aR[0][m] = *(const short8*)(ab + ((size_t)(ob + m * 16 + l15) * 4 + lg) * 8);
        const unsigned short* srow = xs + (size_t)wr * 2048 * 8;
        #pragma unroll
        for (int n = 0; n < 4; ++n) {
            int qq = pb + n * 16 + l15 - 1;
            int qc = qq < 0 ? 0 : (qq > 127 ? 127 : qq);
            int j  = lg ^ ((qc + 1) & 15);
            short8 v = *(const short8*)(srow + ((size_t)qc * 16 + j) * 8);
            bR[0][n] = (qq < 0) ? (short8)(0) : v;
        }
    }

    // ---- 36 phases; phase ph computes (kd=ph>>2, cc=ph&3) ----
    #pragma unroll
    for (int ph = 0; ph < 36; ++ph) {
        const int q = ph & 1;
        // issue gll16 of slice ph+3 (tail: dup slice 35, benign)
        {
            const int pn = (ph + 3 > 35) ? 35 : ph + 3;
            gll16(kT2 + ((size_t)pn * ACH + tid) * 8,
                  xs + (size_t)(XCH + (pn & 3) * ACH + tid) * 8);
        }
        // prefetch phase ph+1 fragments (slice ph+1 resident since end of ph-1)
        if (ph < 35) {
            const int p1  = ph + 1;
            const int kd1 = p1 >> 2, cc1 = p1 & 3;
            const int k1  = kd1 / 3, d1 = kd1 % 3;
            const unsigned short* ab = xs + (size_t)(XCH + (p1 & 3) * ACH) * 8;
            #pragma unroll
            for (int m = 0; m < 4; ++m)
                aR[q ^ 1][m] = *(const short8*)(ab + ((size_t)(ob + m * 16 + l15) * 4 + lg) * 8);
            const unsigned short* srow = xs + (size_t)(wr + k1) * 2048 * 8;
            #pragma unroll
            for (int n = 0; n < 4; ++n) {
                int qq = pb + n * 16 + l15 + d1 - 1;     // -1..128
                int qc = qq < 0 ? 0 : (qq > 127 ? 127 : qq);
                int j  = (cc1 * 4 + lg) ^ ((qc + 1) & 15);
                short8 v = *(const short8*)(srow + ((size_t)qc * 16 + j) * 8);
                bR[q ^ 1][n] = (qq < 0 || qq > 127) ? (short8)(0) : v;
            }
        }
        __builtin_amdgcn_s_setprio(1);
        #pragma unroll
        for (int m = 0; m < 4; ++m)
            #pragma unroll
            for (int n = 0; n < 4; ++n)
                acc[m][n] = __builtin_amdgcn_mfma_f32_16x16x32_bf16(aR[q][m], bR[q][n], acc[m][n], 0, 0, 0);
        __builtin_amdgcn_s_setprio(0);
        // slice ph+2 (issued at ph-1) must be resident for phase ph+1's prefetch
        asm volatile("s_waitcnt vmcnt(1)" ::: "memory");
        __builtin_amdgcn_s_barrier();
    }

    // store: D col = lane&15 -> px, row = (lane>>4)*4 + r -> o
    int row = rp * 2 + wr;
    float* op = out + (size_t)b * COUT * NN * NN + (size_t)row * NN;
    #pragma unroll
    for (int m = 0; m < 4; ++m) {
        #pragma unroll
        for (int n = 0; n < 4; ++n) {
            int p = pb + n * 16 + l15;
            #pragma unroll
            for (int r = 0; r < 4; ++r) {
                int o = ob + m * 16 + lg * 4 + r;
                op[(size_t)o * (NN * NN) + p] = acc[m][n][r];
            }
        }
    }
}

// ---------------------------------------------------------------------------
// fallback: naive direct conv (only if workspace too small)
// ---------------------------------------------------------------------------
__global__ __launch_bounds__(256) void conv_naive_kernel(const float* __restrict__ x,
                                                         const float* __restrict__ kern,
                                                         float* __restrict__ out) {
    size_t idx = (size_t)blockIdx.x * 256 + threadIdx.x;
    int p = idx & 127;
    size_t t = idx >> 7;
    int i = t & 127; t >>= 7;
    int o = t & 127;
    int b = (int)(t >> 7);
    float s = 0.f;
    for (int c = 0; c < CIN; ++c) {
        #pragma unroll
        for (int k = 0; k < 3; ++k) {
            int r = i + k - 1;
            if (r < 0 || r >= NN) continue;
            #pragma unroll
            for (int d = 0; d < 3; ++d) {
                int qq = p + d - 1;
                if (qq < 0 || qq >= NN) continue;
                s += kern[(((size_t)o * CIN + c) * 3 + k) * 3 + d]
                   * x[(((size_t)b * CIN + c) * NN + r) * NN + qq];
            }
        }
    }
    out[idx] = s;
}

extern "C" void kernel_launch(void* const* d_in, const int* in_sizes, int n_in,
                              void* d_out, int out_size, void* d_ws, size_t ws_size,
                              hipStream_t stream) {
    const float* x    = (const float*)d_in[0];
    const float* kern = (const float*)d_in[1];
    float* out = (float*)d_out;

    const size_t xT_bytes  = (size_t)B_ * NN * ROWE * 2;        // 136,314,880
    const size_t kT_bytes  = (size_t)9 * 4 * ACH * 8 * 2;       //     294,912

    if (ws_size >= xT_bytes + kT_bytes) {
        unsigned short* xT  = (unsigned short*)d_ws;
        unsigned short* kT2 = (unsigned short*)((char*)d_ws + xT_bytes);
        hipLaunchKernelGGL(xpose_kernel, dim3(B_ * NN), dim3(256), 0, stream, x, xT);
        hipLaunchKernelGGL(ktrans_kernel, dim3(576), dim3(256), 0, stream, kern, kT2);
        hipLaunchKernelGGL(conv_mfma14_kernel, dim3(2048), dim3(512), 0, stream, xT, kT2, out);
    } else {
        hipLaunchKernelGGL(conv_naive_kernel, dim3(67108864 / 256), dim3(256), 0, stream,
                           x, kern, out);
    }
}

// Round 15
// 256.254 us; speedup vs baseline: 1.5666x; 1.0224x over previous
//
#include <hip/hip_runtime.h>
#include <hip/hip_bf16.h>

#define B_    32
#define CIN   128
#define COUT  128
#define NN    128
#define PPAD  130                   // padded p dimension in xT
#define ROWE  (PPAD * CIN)          // 16640 ushorts per padded xT row
#define XCH   8192                  // x chunks in LDS: 4 rows * 128 px * 16 slots
#define ASL   1024                  // chunks per A slice: 8 cslots x 128 o (16 KB)

typedef __attribute__((ext_vector_type(8))) short short8;
typedef __attribute__((ext_vector_type(4))) float float4v;

static __device__ inline unsigned short f2bf(float f) {
    union { float f; unsigned u; } v; v.f = f;
    unsigned u = v.u;
    unsigned r = u + 0x7FFFu + ((u >> 16) & 1u);   // RNE
    return (unsigned short)(r >> 16);
}

// async 16B global->LDS copy (dest = firstlane base + lane*16; wave-uniform)
static __device__ inline void gll16(const unsigned short* g, unsigned short* l) {
    __builtin_amdgcn_global_load_lds((const __attribute__((address_space(1))) unsigned int*)g,
                                     (__attribute__((address_space(3))) unsigned int*)l,
                                     16, 0, 0);
}

// ---------------------------------------------------------------------------
// x [B][C][N][N] f32 -> xT [B][row][PPAD][128c] bf16, PRE-SWIZZLED:
// 16B chunk at (pp, slot j) holds channels (j ^ (pp&15))*8 .. +7.
// zero cols pp=0,129. One block per (b,row).
// ---------------------------------------------------------------------------
__global__ __launch_bounds__(256) void xpose_kernel(const float* __restrict__ x,
                                                    unsigned short* __restrict__ xT) {
    int b = blockIdx.x >> 7;
    int i = blockIdx.x & 127;
    __shared__ unsigned short tile[CIN * PPAD];   // [c][p], row stride 130
    int tid = threadIdx.x;
    const float* src = x + ((size_t)(b * CIN) * NN + i) * NN;  // x[b][0][i][0]
    #pragma unroll
    for (int e = 0; e < 64; ++e) {
        int idx = e * 256 + tid;
        int c = idx >> 7;
        int p = idx & 127;
        tile[c * PPAD + p] = f2bf(src[(size_t)c * (NN * NN) + p]);
    }
    __syncthreads();
    unsigned short* dst = xT + (size_t)(b * NN + i) * ROWE;
    #pragma unroll
    for (int e = 0; e < 32; ++e) {
        int pi = e * 256 + tid;          // 0..8191
        int c2 = (pi & 63) * 2;
        int p  = pi >> 6;
        ushort2 v;
        v.x = tile[c2 * PPAD + p];
        v.y = tile[(c2 + 1) * PPAD + p];
        int pp = p + 1;
        int sl = (c2 >> 3) ^ (pp & 15);              // baked XOR swizzle
        *(ushort2*)(dst + (size_t)pp * CIN + sl * 8 + (c2 & 7)) = v;
    }
    if (tid < 128) {                                  // zero pad cols
        dst[tid] = 0;
        dst[(size_t)129 * CIN + tid] = 0;
    }
}

// ---------------------------------------------------------------------------
// kernel [O][C][3][3] f32 -> kT2 [kd][cslot16][o][8c] bf16 (kd = k*3+d)
// slice sl = kd*2+h covers cslots h*8..h*8+7 = chunks [(kd*16+h*8)*128, +1024)
// ---------------------------------------------------------------------------
__global__ __launch_bounds__(256) void ktrans_kernel(const float* __restrict__ kern,
                                                     unsigned short* __restrict__ kT2) {
    int idx = blockIdx.x * 256 + threadIdx.x;     // 0..147455
    if (idx >= COUT * CIN * 9) return;
    int c  = idx & 127;
    int o  = (idx >> 7) & 127;
    int kd = idx >> 14;                           // 0..8
    int k = kd / 3, d = kd % 3;
    float v = kern[(((size_t)o * CIN + c) * 3 + k) * 3 + d];
    kT2[((size_t)(kd * 16 + (c >> 3)) * 128 + o) * 8 + (c & 7)] = f2bf(v);
}

// ---------------------------------------------------------------------------
// main v15: FAT WAVES. Block = 2 rows x 128 px x 128 o, 256 thr = 4 waves,
// wave = 128 o x 64 px x 1 row (acc[8][4]). 1 wave/SIMD, VGPR cap lifted via
// __launch_bounds__(256,1). 18 phases (kd x channel-half, 64 MFMA/wave each).
// LDS = unpadded x-tile 128 KB (p-edge clamp+mask) + A ring-2 x 16 KB
// = 163,840 B exactly. A-slice issued at phase top; vmcnt(0)+barrier at end.
// ---------------------------------------------------------------------------
__global__ __launch_bounds__(256, 1) void conv_mfma15_kernel(
        const unsigned short* __restrict__ xT,
        const unsigned short* __restrict__ kT2,
        float* __restrict__ out) {
    __shared__ unsigned short xs[(XCH + 2 * ASL) * 8];   // 163,840 B

    // bijective XCD swizzle: 2048 blocks, 8 XCDs, 256-block contiguous slabs
    int wg = blockIdx.x;
    int lb = (wg & 7) * 256 + (wg >> 3);
    int b  = lb >> 6;            // image
    int rp = lb & 63;            // row pair

    int tid  = threadIdx.x;
    int lane = tid & 63;
    int wave = tid >> 6;           // 0..3
    int wr = wave >> 1;            // row of pair (0/1)
    int wp = wave & 1;             // px 64-half
    int pb  = wp * 64;
    int l15 = lane & 15;
    int lg  = lane >> 4;           // 0..3

    // ---- prologue: stage x tile (32 chunks/thread) + A slice 0 ----
    {
        const unsigned short* xrow_base = xT + (size_t)b * NN * ROWE;
        #pragma unroll
        for (int s = 0; s < 32; ++s) {
            int W   = s * 256 + tid;            // 0..8191
            int r   = W >> 11;                  // 0..3 (wave-uniform: 64|2048)
            int rem = W & 2047;                 // p*16 + j
            int grow = rp * 2 - 1 + r;          // -1..128
            int growc = grow < 0 ? 0 : (grow > NN - 1 ? NN - 1 : grow);
            // src chunk = (p+1)*16 + j  (skip pad col 0)
            gll16(xrow_base + (size_t)growc * ROWE + (size_t)(rem + 16) * 8,
                  xs + (size_t)W * 8);
        }
        #pragma unroll
        for (int s = 0; s < 4; ++s) {
            int W = s * 256 + tid;
            gll16(kT2 + (size_t)W * 8, xs + (size_t)(XCH + W) * 8);
        }
    }
    asm volatile("s_waitcnt vmcnt(0)" ::: "memory");
    __builtin_amdgcn_s_barrier();

    // ---- zero halo rows outside the image (block-uniform) ----
    if (rp == 0) {
        for (int W = tid; W < 2048; W += 256)
            *(short8*)(xs + (size_t)W * 8) = (short8)(0);
    }
    if (rp == 63) {
        for (int W = 3 * 2048 + tid; W < 4 * 2048; W += 256)
            *(short8*)(xs + (size_t)W * 8) = (short8)(0);
    }
    if (rp == 0 || rp == 63) {
        asm volatile("s_waitcnt lgkmcnt(0)" ::: "memory");
        __builtin_amdgcn_s_barrier();
    }

    float4v acc[8][4];
    #pragma unroll
    for (int m = 0; m < 8; ++m)
        #pragma unroll
        for (int n = 0; n < 4; ++n)
            acc[m][n] = (float4v)(0.0f);

    // ---- 18 phases: (k, d, h); slice sl = (k*3+d)*2 + h; A buf = sl & 1 ----
    #pragma unroll
    for (int k = 0; k < 3; ++k) {
        #pragma unroll
        for (int d = 0; d < 3; ++d) {
            #pragma unroll
            for (int h = 0; h < 2; ++h) {
                const int sl = (k * 3 + d) * 2 + h;
                // stage next A slice (issue early; ~full phase to land)
                if (sl < 17) {
                    const int sn  = sl + 1;
                    const int kdn = sn >> 1, hn = sn & 1;
                    #pragma unroll
                    for (int s = 0; s < 4; ++s) {
                        int W = s * 256 + tid;
                        gll16(kT2 + ((size_t)(kdn * 16 + hn * 8) * 128 + W) * 8,
                              xs + (size_t)(XCH + (sn & 1) * ASL + W) * 8);
                    }
                }
                const unsigned short* ab   = xs + (size_t)(XCH + (sl & 1) * ASL) * 8;
                const unsigned short* srow = xs + (size_t)(wr + k) * 2048 * 8;
                #pragma unroll
                for (int c2 = 0; c2 < 2; ++c2) {
                    short8 a[8], bt[4];
                    #pragma unroll
                    for (int m = 0; m < 8; ++m)
                        a[m] = *(const short8*)(ab +
                            ((size_t)((c2 * 4 + lg) * 128) + m * 16 + l15) * 8);
                    #pragma unroll
                    for (int n = 0; n < 4; ++n) {
                        int qq = pb + n * 16 + l15 + d - 1;      // -1..128
                        int qc = qq < 0 ? 0 : (qq > 127 ? 127 : qq);
                        int j  = (h * 8 + c2 * 4 + lg) ^ ((qc + 1) & 15);
                        short8 v = *(const short8*)(srow + ((size_t)qc * 16 + j) * 8);
                        bt[n] = (qq < 0 || qq > 127) ? (short8)(0) : v;
                    }
                    #pragma unroll
                    for (int m = 0; m < 8; ++m)
                        #pragma unroll
                        for (int n = 0; n < 4; ++n)
                            acc[m][n] = __builtin_amdgcn_mfma_f32_16x16x32_bf16(a[m], bt[n], acc[m][n], 0, 0, 0);
                }
                asm volatile("s_waitcnt vmcnt(0)" ::: "memory");
                __builtin_amdgcn_s_barrier();
            }
        }
    }

    // store: D col = lane&15 -> px, row = (lane>>4)*4 + r -> o (per 16x16 frag)
    int row = rp * 2 + wr;
    float* op = out + (size_t)b * COUT * NN * NN + (size_t)row * NN;
    #pragma unroll
    for (int m = 0; m < 8; ++m) {
        #pragma unroll
        for (int n = 0; n < 4; ++n) {
            int p = pb + n * 16 + l15;
            #pragma unroll
            for (int r = 0; r < 4; ++r) {
                int o = m * 16 + lg * 4 + r;
                op[(size_t)o * (NN * NN) + p] = acc[m][n][r];
            }
        }
    }
}

// ---------------------------------------------------------------------------
// fallback: naive direct conv (only if workspace too small)
// ---------------------------------------------------------------------------
__global__ __launch_bounds__(256) void conv_naive_kernel(const float* __restrict__ x,
                                                         const float* __restrict__ kern,
                                                         float* __restrict__ out) {
    size_t idx = (size_t)blockIdx.x * 256 + threadIdx.x;
    int p = idx & 127;
    size_t t = idx >> 7;
    int i = t & 127; t >>= 7;
    int o = t & 127;
    int b = (int)(t >> 7);
    float s = 0.f;
    for (int c = 0; c < CIN; ++c) {
        #pragma unroll
        for (int k = 0; k < 3; ++k) {
            int r = i + k - 1;
            if (r < 0 || r >= NN) continue;
            #pragma unroll
            for (int d = 0; d < 3; ++d) {
                int qq = p + d - 1;
                if (qq < 0 || qq >= NN) continue;
                s += kern[(((size_t)o * CIN + c) * 3 + k) * 3 + d]
                   * x[(((size_t)b * CIN + c) * NN + r) * NN + qq];
            }
        }
    }
    out[idx] = s;
}

extern "C" void kernel_launch(void* const* d_in, const int* in_sizes, int n_in,
                              void* d_out, int out_size, void* d_ws, size_t ws_size,
                              hipStream_t stream) {
    const float* x    = (const float*)d_in[0];
    const float* kern = (const float*)d_in[1];
    float* out = (float*)d_out;

    const size_t xT_bytes  = (size_t)B_ * NN * ROWE * 2;        // 136,314,880
    const size_t kT_bytes  = (size_t)9 * 16 * 128 * 8 * 2;      //     294,912

    if (ws_size >= xT_bytes + kT_bytes) {
        unsigned short* xT  = (unsigned short*)d_ws;
        unsigned short* kT2 = (unsigned short*)((char*)d_ws + xT_bytes);
        hipLaunchKernelGGL(xpose_kernel, dim3(B_ * NN), dim3(256), 0, stream, x, xT);
        hipLaunchKernelGGL(ktrans_kernel, dim3(576), dim3(256), 0, stream, kern, kT2);
        hipLaunchKernelGGL(conv_mfma15_kernel, dim3(2048), dim3(256), 0, stream, xT, kT2, out);
    } else {
        hipLaunchKernelGGL(conv_naive_kernel, dim3(67108864 / 256), dim3(256), 0, stream,
                           x, kern, out);
    }
}